// Round 5
// baseline (75.925 us; speedup 1.0000x reference)
//
#include <hip/hip_runtime.h>

#define N_NODES 10000
#define FEATS 32
#define HEADS 4
#define SAMPLES 256
#define N_BATCH 2048
#define CHUNK 64                        // samples per chunk (one per lane)
#define NCHUNK 8                        // 512 samples / 64
#define NGROUP 40                       // ceil(N_NODES / 256)
#define NWORDS (NGROUP * 4)             // 160 u64 words per mask row

// Direct global->LDS DMA, 16 B per lane. Dest is wave-uniform base + lane*16.
__device__ __forceinline__ void gload_lds16(const float* g, float* l) {
    __builtin_amdgcn_global_load_lds(
        (const __attribute__((address_space(1))) void*)g,
        (__attribute__((address_space(3))) void*)l,
        16, 0, 0);
}

// ---------------- Kernel 1: edge_mat rows -> sign bitmasks in d_ws ----------
// Block n: row dst (r=0, side0 via symmetry) and row src (r=1, side1).
// Pure streaming HBM (80 KB/block sequential); writes 2.5 KB bitmask; zeroes
// out[n] so k2 can atomically accumulate (replays stay idempotent).
__global__ __launch_bounds__(256) void mask_kernel(
    const int* __restrict__ edge,
    const float* __restrict__ edge_mat,
    unsigned long long* __restrict__ ws_mask,
    float* __restrict__ out)
{
    const int n    = blockIdx.x;
    const int tid  = threadIdx.x;
    const int wave = tid >> 6;
    const int lane = tid & 63;

    const int src = edge[2 * n];
    const int dst = edge[2 * n + 1];
    if (tid == 0) out[n] = 0.f;

    unsigned long long* wsn = ws_mask + (size_t)n * 2 * NWORDS;

    #pragma unroll
    for (int r = 0; r < 2; ++r) {
        const float* rp = edge_mat + (size_t)(r ? src : dst) * N_NODES;
        for (int g = wave; g < NGROUP; g += 4) {
            int base = g * 256 + lane * 4;
            float4 v = make_float4(-1.f, -1.f, -1.f, -1.f);
            if (base < N_NODES) v = *(const float4*)(rp + base);
            unsigned long long b0 = __ballot(v.x > 0.f);
            unsigned long long b1 = __ballot(v.y > 0.f);
            unsigned long long b2 = __ballot(v.z > 0.f);
            unsigned long long b3 = __ballot(v.w > 0.f);
            if (lane < 4) {
                unsigned long long b = lane == 0 ? b0 : lane == 1 ? b1
                                     : lane == 2 ? b2 : b3;
                wsn[r * NWORDS + g * 4 + lane] = b;
            }
        }
    }
}

// ---------------- Kernel 2: main compute, one WAVE per (edge, head) ---------
// blockIdx.x = i: h = i & 3, n = i >> 2. Round-robin XCD (i % 8) keeps each
// XCD's pos-gathers inside pos[h] (1.28 MB, L2-resident).
//
// Software pipeline (T3/T4 counted-vmcnt, no barriers — single-wave block):
//   iter c: issue staging(c+1) -> buf[(c+1)&1] (8 gload_lds)
//           prefetch mids(c+2) (1 load)
//           em from LDS bitmask (m_cur)
//           s_waitcnt vmcnt(9)  [= newer in-flight ops; in-order retirement
//                                guarantees staging(c) landed]   (8 at c=6, 0 at c=7)
//           compute chunk c from buf[c&1]
// Staging swizzle is both-sides: linear DMA dest; SOURCE chunk pre-swizzled
// (l&7)^(l>>3); READ logical chunk q from physical slot q^(lane&7).
__global__ __launch_bounds__(64, 2) void madgraph_kernel(
    const int* __restrict__ edge,
    const int* __restrict__ mid0,
    const int* __restrict__ mid1,
    const float* __restrict__ pos,
    const float* __restrict__ field,
    const float* __restrict__ unc,
    const unsigned long long* __restrict__ ws_mask,
    float* __restrict__ out)
{
    const int i    = blockIdx.x;
    const int h    = i & 3;
    const int n    = i >> 2;
    const int lane = threadIdx.x;

    __shared__ float s_rows[2][CHUNK][FEATS];         // 16 KB double buffer
    __shared__ unsigned long long s_mask[2 * NWORDS]; // 2.5 KB

    const int src = edge[2 * n];
    const int dst = edge[2 * n + 1];
    const float U = unc[0];

    // Stage this edge's two bitmask rows (coalesced 2.5 KB).
    const unsigned long long* wsn = ws_mask + (size_t)n * 2 * NWORDS;
    #pragma unroll
    for (int w = 0; w < 2 * NWORDS / 64; ++w)
        s_mask[w * 64 + lane] = wsn[w * 64 + lane];

    // Anchor pos/field rows for BOTH sides, in registers (32 float4).
    float4 A[2][8], F[2][8];
    #pragma unroll
    for (int sd = 0; sd < 2; ++sd) {
        const float* pa = pos   + ((size_t)h * N_NODES + (sd ? dst : src)) * FEATS;
        const float* pf = field + ((size_t)h * N_NODES + (sd ? src : dst)) * FEATS;
        #pragma unroll
        for (int q = 0; q < 8; ++q) {
            A[sd][q] = ((const float4*)pa)[q];
            F[sd][q] = ((const float4*)pf)[q];
        }
    }

    const size_t sb = ((size_t)h * N_BATCH + n) * SAMPLES;
    int mc = mid0[sb + lane];        // samples, chunk 0
    int mn = mid0[sb + 64 + lane];   // samples, chunk 1
    const int qsrc = (lane & 7) ^ (lane >> 3);

    // Order all prologue loads before staging(0) so counted waits stay valid.
    asm volatile("" ::: "memory");

    // Stage chunk 0 into buf0.
    #pragma unroll
    for (int t = 0; t < 8; ++t) {
        int mrow = __shfl(mc, t * 8 + (lane >> 3));
        gload_lds16(pos + ((size_t)h * N_NODES + mrow) * FEATS + qsrc * 4,
                    &s_rows[0][t * 8][0]);
    }

    float num = 0.f, den = 0.f;

    #pragma unroll
    for (int c = 0; c < NCHUNK; ++c) {
        const int side = c >> 2;

        // (A) issue staging for chunk c+1
        if (c < 7) {
            #pragma unroll
            for (int t = 0; t < 8; ++t) {
                int mrow = __shfl(mn, t * 8 + (lane >> 3));
                gload_lds16(pos + ((size_t)h * N_NODES + mrow) * FEATS + qsrc * 4,
                            &s_rows[(c + 1) & 1][t * 8][0]);
            }
        }
        // (B) prefetch mids for chunk c+2
        int mn2 = 0;
        if (c < 6) {
            const int* mids2 = ((c + 2) >> 2) ? mid1 : mid0;
            mn2 = mids2[sb + ((c + 2) & 3) * 64 + lane];
        }
        // (C) edge term from LDS bitmask (no global load)
        const unsigned long long wbits =
            s_mask[side * NWORDS + ((mc >> 8) << 2) + (mc & 3)];
        const float em = ((wbits >> ((mc >> 2) & 63)) & 1ull) ? U : -U;

        // (D) counted wait: staging(c) complete; staging(c+1)+mids(c+2) in flight
        if (c <= 5)      asm volatile("s_waitcnt vmcnt(9)" ::: "memory");
        else if (c == 6) asm volatile("s_waitcnt vmcnt(8)" ::: "memory");
        else             asm volatile("s_waitcnt vmcnt(0)" ::: "memory");
        __builtin_amdgcn_sched_barrier(0);

        // (E) compute chunk c from buf[c&1]
        float dot = 0.f, nrm = 0.f;
        #pragma unroll
        for (int q = 0; q < 8; ++q) {
            int s = q ^ (lane & 7);
            float4 b = *(const float4*)&s_rows[c & 1][lane][s * 4];
            float4 a = A[side][q], fv = F[side][q];
            float dx = a.x - b.x, dy = a.y - b.y, dz = a.z - b.z, dw = a.w - b.w;
            dot += dx * fv.x + dy * fv.y + dz * fv.z + dw * fv.w;
            nrm += dx * dx + dy * dy + dz * dz + dw * dw;
        }

        float logit = dot + em;
        float dist  = sqrtf(nrm);
        float e     = __expf(1.0f - dist);
        num += logit * e;
        den += e;

        mc = mn; mn = mn2;
    }

    #pragma unroll
    for (int off = 32; off > 0; off >>= 1) {
        num += __shfl_xor(num, off);
        den += __shfl_xor(den, off);
    }
    if (lane == 0) {
        // +8 sentinels: exp(1-1)=1 each. Head-mean via atomic accumulate
        // (k1 zeroed out[n] earlier in this same launch).
        atomicAdd(out + n, 0.25f * (num / (den + 8.0f)));
    }
}

extern "C" void kernel_launch(void* const* d_in, const int* in_sizes, int n_in,
                              void* d_out, int out_size, void* d_ws, size_t ws_size,
                              hipStream_t stream) {
    const int*   edge     = (const int*)  d_in[0];
    const int*   mid0     = (const int*)  d_in[1];
    const int*   mid1     = (const int*)  d_in[2];
    const float* pos      = (const float*)d_in[3];
    const float* field    = (const float*)d_in[4];
    const float* unc      = (const float*)d_in[5];
    const float* edge_mat = (const float*)d_in[6];
    float*       out      = (float*)d_out;
    unsigned long long* ws_mask = (unsigned long long*)d_ws; // 5.24 MB used

    mask_kernel<<<N_BATCH, 256, 0, stream>>>(edge, edge_mat, ws_mask, out);
    madgraph_kernel<<<N_BATCH * HEADS, 64, 0, stream>>>(edge, mid0, mid1, pos,
                                                        field, unc, ws_mask, out);
}

// Round 6
// 71.932 us; speedup vs baseline: 1.0555x; 1.0555x over previous
//
#include <hip/hip_runtime.h>

#define N_NODES 10000
#define FEATS 32
#define HEADS 4
#define SAMPLES 256
#define N_BATCH 2048
#define NGROUP 40                       // ceil(N_NODES / 256)
#define NWORDS (NGROUP * 4)             // 160 u64 words per mask row

// Direct global->LDS DMA, 16 B per lane. Dest is wave-uniform base + lane*16.
__device__ __forceinline__ void gload_lds16(const float* g, float* l) {
    __builtin_amdgcn_global_load_lds(
        (const __attribute__((address_space(1))) void*)g,
        (__attribute__((address_space(3))) void*)l,
        16, 0, 0);
}

// ---------------- Kernel 1: edge_mat rows -> sign bitmasks in d_ws ----------
// Block n: row dst (r=0, side0 via symmetry) and row src (r=1, side1).
// Pure streaming HBM (80 KB/block sequential); writes 2.5 KB bitmask; zeroes
// out[n] so k2 can atomically accumulate (replays stay idempotent).
__global__ __launch_bounds__(256) void mask_kernel(
    const int* __restrict__ edge,
    const float* __restrict__ edge_mat,
    unsigned long long* __restrict__ ws_mask,
    float* __restrict__ out)
{
    const int n    = blockIdx.x;
    const int tid  = threadIdx.x;
    const int wave = tid >> 6;
    const int lane = tid & 63;

    const int src = edge[2 * n];
    const int dst = edge[2 * n + 1];
    if (tid == 0) out[n] = 0.f;

    unsigned long long* wsn = ws_mask + (size_t)n * 2 * NWORDS;

    #pragma unroll
    for (int r = 0; r < 2; ++r) {
        const float* rp = edge_mat + (size_t)(r ? src : dst) * N_NODES;
        for (int g = wave; g < NGROUP; g += 4) {
            int base = g * 256 + lane * 4;
            float4 v = make_float4(-1.f, -1.f, -1.f, -1.f);
            if (base < N_NODES) v = *(const float4*)(rp + base);
            unsigned long long b0 = __ballot(v.x > 0.f);
            unsigned long long b1 = __ballot(v.y > 0.f);
            unsigned long long b2 = __ballot(v.z > 0.f);
            unsigned long long b3 = __ballot(v.w > 0.f);
            if (lane < 4) {
                unsigned long long b = lane == 0 ? b0 : lane == 1 ? b1
                                     : lane == 2 ? b2 : b3;
                wsn[r * NWORDS + g * 4 + lane] = b;
            }
        }
    }
}

// ---------------- Kernel 2: main compute, one WAVE per (edge, head) ---------
// blockIdx.x = i: h = i & 3, n = i >> 2. Round-robin XCD (i % 8) keeps each
// XCD's pos-gathers inside pos[h] (1.28 MB, L2-resident).
//
// Pipeline (depth-1, counted vmcnt, zero in-loop global loads):
//   16 half-chunks of 32 rows (4 KB), double-buffered (2 x 4 KB LDS).
//   iter hc: issue staging(hc+1) [4 gload_lds] -> em lookup ->
//            s_waitcnt vmcnt(4)  [guarantees staging(hc) retired] -> compute.
//   All mids preloaded to registers (mm[8], static index) so the loop's
//   vmcnt queue holds ONLY staging ops -> no compiler-forced drains (R4 bug).
//
// Lane-pair sample split: pair p = lane>>1 owns sample (hc&1)*32+p; even lane
// computes feats 0-15, odd 16-31; one shfl_xor(1) combines dot/nrm. Both
// lanes accumulate (num,den doubled; folded via den+16 at the end).
// Staging swizzle both-sides: linear DMA dest; SOURCE chunk pre-swizzled
// (l&7)^(l>>3); READ logical chunk q from physical slot q^(p&7).
__global__ __launch_bounds__(64) void madgraph_kernel(
    const int* __restrict__ edge,
    const int* __restrict__ mid0,
    const int* __restrict__ mid1,
    const float* __restrict__ pos,
    const float* __restrict__ field,
    const float* __restrict__ unc,
    const unsigned long long* __restrict__ ws_mask,
    float* __restrict__ out)
{
    const int i    = blockIdx.x;
    const int h    = i & 3;
    const int n    = i >> 2;
    const int lane = threadIdx.x;

    __shared__ float s_rows[2][32][FEATS];            // 2 x 4 KB double buffer
    __shared__ unsigned long long s_mask[2 * NWORDS]; // 2.5 KB

    const int src = edge[2 * n];
    const int dst = edge[2 * n + 1];
    const float U = unc[0];

    // Stage this edge's two bitmask rows (coalesced 2.5 KB).
    const unsigned long long* wsn = ws_mask + (size_t)n * 2 * NWORDS;
    #pragma unroll
    for (int w = 0; w < 2 * NWORDS / 64; ++w)
        s_mask[w * 64 + lane] = wsn[w * 64 + lane];

    const float* posh   = pos   + (size_t)h * N_NODES * FEATS;
    const float* fieldh = field + (size_t)h * N_NODES * FEATS;

    const int p = lane >> 1;   // pair (sample) index within half-chunk
    const int e = lane & 1;    // feature-half selector

    // Per-lane anchor/field feature-half, side 0 (anchor pos[src], field[dst]).
    float4 Ao[4], Fo[4];
    {
        const float* pa = posh   + (size_t)src * FEATS;
        const float* pf = fieldh + (size_t)dst * FEATS;
        #pragma unroll
        for (int k = 0; k < 4; ++k) {
            Ao[k] = ((const float4*)pa)[e * 4 + k];
            Fo[k] = ((const float4*)pf)[e * 4 + k];
        }
    }

    // ALL mids in registers: mm[c] = sample (c*64 + lane), statically indexed.
    const size_t sb = ((size_t)h * N_BATCH + n) * SAMPLES;
    int mm[8];
    #pragma unroll
    for (int c = 0; c < 8; ++c)
        mm[c] = (c < 4 ? mid0 : mid1)[sb + (c & 3) * 64 + lane];

    const int qsrc = (lane & 7) ^ (lane >> 3); // pre-swizzled source chunk

    // Fence: every prologue VMEM/LDS op retired; loop vmcnt = staging only.
    asm volatile("s_waitcnt vmcnt(0) lgkmcnt(0)" ::: "memory");
    __builtin_amdgcn_sched_barrier(0);

    // Stage half-chunk 0 into buf 0.
    #pragma unroll
    for (int t = 0; t < 4; ++t) {
        int rid = __shfl(mm[0], t * 8 + (lane >> 3));
        gload_lds16(posh + (size_t)rid * FEATS + qsrc * 4, &s_rows[0][t * 8][0]);
    }

    float num = 0.f, den = 0.f;

    #pragma unroll
    for (int hc = 0; hc < 16; ++hc) {
        const int c    = hc >> 1;   // chunk 0..7 (compile-time under unroll)
        const int side = hc >> 3;   // 0 for hc<8, 1 after

        if (hc == 8) {
            // Side switch: anchor pos[dst], field[src]. Compiler waits for
            // these with vmcnt(4) (4 staging ops newer) — no full drain.
            const float* pa = posh   + (size_t)dst * FEATS;
            const float* pf = fieldh + (size_t)src * FEATS;
            #pragma unroll
            for (int k = 0; k < 4; ++k) {
                Ao[k] = ((const float4*)pa)[e * 4 + k];
                Fo[k] = ((const float4*)pf)[e * 4 + k];
            }
        }

        // (A) issue staging for half-chunk hc+1 (into the other buffer)
        if (hc < 15) {
            const int c1 = (hc + 1) >> 1, hf1 = (hc + 1) & 1;
            #pragma unroll
            for (int t = 0; t < 4; ++t) {
                int rid = __shfl(mm[c1], hf1 * 32 + t * 8 + (lane >> 3));
                gload_lds16(posh + (size_t)rid * FEATS + qsrc * 4,
                            &s_rows[(hc + 1) & 1][t * 8][0]);
            }
        }

        // (B) edge term for this pair's sample (register shfl + LDS bitmask)
        const int m = __shfl(mm[c], (hc & 1) * 32 + p);
        const unsigned long long wbits =
            s_mask[side * NWORDS + ((m >> 8) << 2) + (m & 3)];
        const float em = ((wbits >> ((m >> 2) & 63)) & 1ull) ? U : -U;

        // (C) counted wait: staging(hc) retired; staging(hc+1) stays in flight
        if (hc < 15) asm volatile("s_waitcnt vmcnt(4)" ::: "memory");
        else         asm volatile("s_waitcnt vmcnt(0)" ::: "memory");
        __builtin_amdgcn_sched_barrier(0);

        // (D) compute: this lane's feature-half of sample p
        float dh = 0.f, nh = 0.f;
        #pragma unroll
        for (int k = 0; k < 4; ++k) {
            const int s = (e * 4 + k) ^ (p & 7);   // swizzled physical slot
            float4 b = *(const float4*)&s_rows[hc & 1][p][s * 4];
            float4 a = Ao[k], fv = Fo[k];
            float dx = a.x - b.x, dy = a.y - b.y, dz = a.z - b.z, dw = a.w - b.w;
            dh += dx * fv.x + dy * fv.y + dz * fv.z + dw * fv.w;
            nh += dx * dx + dy * dy + dz * dz + dw * dw;
        }
        float dot = dh + __shfl_xor(dh, 1);
        float nrm = nh + __shfl_xor(nh, 1);

        float logit = dot + em;
        float wgt   = __expf(1.0f - sqrtf(nrm));
        num += logit * wgt;   // both lanes of the pair accumulate (2x, folded below)
        den += wgt;
    }

    #pragma unroll
    for (int off = 32; off > 0; off >>= 1) {
        num += __shfl_xor(num, off);
        den += __shfl_xor(den, off);
    }
    if (lane == 0) {
        // num,den are 2x the true sums; sentinels add 8 true -> +16 doubled.
        // 0.25*(2N)/(2D+16) == 0.25*N/(D+8). k1 zeroed out[n] this launch.
        atomicAdd(out + n, 0.25f * (num / (den + 16.0f)));
    }
}

extern "C" void kernel_launch(void* const* d_in, const int* in_sizes, int n_in,
                              void* d_out, int out_size, void* d_ws, size_t ws_size,
                              hipStream_t stream) {
    const int*   edge     = (const int*)  d_in[0];
    const int*   mid0     = (const int*)  d_in[1];
    const int*   mid1     = (const int*)  d_in[2];
    const float* pos      = (const float*)d_in[3];
    const float* field    = (const float*)d_in[4];
    const float* unc      = (const float*)d_in[5];
    const float* edge_mat = (const float*)d_in[6];
    float*       out      = (float*)d_out;
    unsigned long long* ws_mask = (unsigned long long*)d_ws; // 5.24 MB used

    mask_kernel<<<N_BATCH, 256, 0, stream>>>(edge, edge_mat, ws_mask, out);
    madgraph_kernel<<<N_BATCH * HEADS, 64, 0, stream>>>(edge, mid0, mid1, pos,
                                                        field, unc, ws_mask, out);
}

// Round 7
// 64.495 us; speedup vs baseline: 1.1772x; 1.1153x over previous
//
#include <hip/hip_runtime.h>

#define N_NODES 10000
#define FEATS 32
#define HEADS 4
#define SAMPLES 256
#define N_BATCH 2048
#define NGROUP 40                       // ceil(N_NODES / 256)
#define NWORDS (NGROUP * 4)             // 160 u64 words per mask row

// ---------------- Kernel 1: edge_mat rows -> sign bitmasks in d_ws ----------
// Block n: row dst (r=0, side0 via symmetry) and row src (r=1, side1).
// Pure streaming HBM (80 KB/block sequential); writes 2.5 KB bitmask; zeroes
// out[n] so k2 can atomically accumulate (replays stay idempotent).
__global__ __launch_bounds__(256) void mask_kernel(
    const int* __restrict__ edge,
    const float* __restrict__ edge_mat,
    unsigned long long* __restrict__ ws_mask,
    float* __restrict__ out)
{
    const int n    = blockIdx.x;
    const int tid  = threadIdx.x;
    const int wave = tid >> 6;
    const int lane = tid & 63;

    const int src = edge[2 * n];
    const int dst = edge[2 * n + 1];
    if (tid == 0) out[n] = 0.f;

    unsigned long long* wsn = ws_mask + (size_t)n * 2 * NWORDS;

    #pragma unroll
    for (int r = 0; r < 2; ++r) {
        const float* rp = edge_mat + (size_t)(r ? src : dst) * N_NODES;
        for (int g = wave; g < NGROUP; g += 4) {
            int base = g * 256 + lane * 4;
            float4 v = make_float4(-1.f, -1.f, -1.f, -1.f);
            if (base < N_NODES) v = *(const float4*)(rp + base);
            unsigned long long b0 = __ballot(v.x > 0.f);
            unsigned long long b1 = __ballot(v.y > 0.f);
            unsigned long long b2 = __ballot(v.z > 0.f);
            unsigned long long b3 = __ballot(v.w > 0.f);
            if (lane < 4) {
                unsigned long long b = lane == 0 ? b0 : lane == 1 ? b1
                                     : lane == 2 ? b2 : b3;
                wsn[r * NWORDS + g * 4 + lane] = b;
            }
        }
    }
}

// ---------------- Kernel 2: register-direct gather, 4 lanes per row ---------
// Block b in [0,2048): head h = b & 3; wave w handles edge n = (b>>2) + 512w.
// Round-robin XCD (b % 8) => XCD x only ever touches pos[x & 3] (1.28 MB,
// L2-resident). No LDS row staging: lane l loads chunks (l&3) and (l&3)+4 of
// row group g = l>>2 (each load instr = 16 rows x contiguous 64 B = optimal
// coalescing), computes an 8-feat partial, and a 2-level shfl_xor butterfly
// produces full dot/nrm on all 4 lanes. em/exp/acc run redundantly per lane
// (wave-level cost identical to masked); each sample thus counted 4x ->
// folded via den+32 at the end. LDS = per-wave 2.5 KB bitmasks only; no
// barriers at all (wave-private LDS).
__global__ __launch_bounds__(256) void madgraph_kernel(
    const int* __restrict__ edge,
    const int* __restrict__ mid0,
    const int* __restrict__ mid1,
    const float* __restrict__ pos,
    const float* __restrict__ field,
    const float* __restrict__ unc,
    const unsigned long long* __restrict__ ws_mask,
    float* __restrict__ out)
{
    const int b    = blockIdx.x;
    const int h    = b & 3;
    const int tid  = threadIdx.x;
    const int w    = tid >> 6;            // wave -> edge slot
    const int lane = tid & 63;
    const int n    = (b >> 2) + 512 * w;  // this wave's edge

    __shared__ unsigned long long s_mask[4][2 * NWORDS]; // 4 x 2.5 KB

    const int src = edge[2 * n];
    const int dst = edge[2 * n + 1];
    const float U = unc[0];

    // Stage this wave's edge bitmasks (320 u64 = 5 per lane, coalesced).
    const unsigned long long* wsn = ws_mask + (size_t)n * 2 * NWORDS;
    #pragma unroll
    for (int k = 0; k < 5; ++k)
        s_mask[w][k * 64 + lane] = wsn[k * 64 + lane];

    const float* posh   = pos   + (size_t)h * N_NODES * FEATS;
    const float* fieldh = field + (size_t)h * N_NODES * FEATS;

    const int q = lane & 3;    // lane's chunk pair: q and q+4
    const int g = lane >> 2;   // row-group index within 16

    // Anchor/field chunks for both sides (8 float4 = 32 VGPRs).
    float4 A[2][2], F[2][2];
    #pragma unroll
    for (int sd = 0; sd < 2; ++sd) {
        const float4* pa = (const float4*)(posh   + (size_t)(sd ? dst : src) * FEATS);
        const float4* pf = (const float4*)(fieldh + (size_t)(sd ? src : dst) * FEATS);
        A[sd][0] = pa[q];
        A[sd][1] = pa[q + 4];
        F[sd][0] = pf[q];
        F[sd][1] = pf[q + 4];
    }

    // All mids in registers (statically indexed under full unroll).
    const size_t sb = ((size_t)h * N_BATCH + n) * SAMPLES;
    int mm[8];
    #pragma unroll
    for (int c = 0; c < 8; ++c)
        mm[c] = (c < 4 ? mid0 : mid1)[sb + (c & 3) * 64 + lane];

    float num = 0.f, den = 0.f;

    #pragma unroll
    for (int c = 0; c < 8; ++c) {
        const int side = c >> 2;
        #pragma unroll
        for (int t = 0; t < 4; ++t) {
            // Row for this lane's 4-lane group (16 rows per t).
            const int m = __shfl(mm[c], t * 16 + g);
            const float4* rp = (const float4*)(posh + (size_t)m * FEATS);
            float4 b0 = rp[q];
            float4 b1 = rp[q + 4];

            float dh = 0.f, nh = 0.f;
            {
                float4 a = A[side][0], f = F[side][0];
                float dx = a.x - b0.x, dy = a.y - b0.y,
                      dz = a.z - b0.z, dw = a.w - b0.w;
                dh += dx * f.x + dy * f.y + dz * f.z + dw * f.w;
                nh += dx * dx + dy * dy + dz * dz + dw * dw;
            }
            {
                float4 a = A[side][1], f = F[side][1];
                float dx = a.x - b1.x, dy = a.y - b1.y,
                      dz = a.z - b1.z, dw = a.w - b1.w;
                dh += dx * f.x + dy * f.y + dz * f.z + dw * f.w;
                nh += dx * dx + dy * dy + dz * dz + dw * dw;
            }
            // 2-level butterfly across the 4-lane group -> full dot/nrm.
            dh += __shfl_xor(dh, 1); nh += __shfl_xor(nh, 1);
            dh += __shfl_xor(dh, 2); nh += __shfl_xor(nh, 2);

            // edge term from LDS bitmask (broadcast within group).
            const unsigned long long wbits =
                s_mask[w][side * NWORDS + ((m >> 8) << 2) + (m & 3)];
            const float em = ((wbits >> ((m >> 2) & 63)) & 1ull) ? U : -U;

            const float wgt = __expf(1.0f - sqrtf(nh));
            num += (dh + em) * wgt;   // each sample counted by 4 lanes
            den += wgt;
        }
    }

    // Wave-wide butterfly reduction (64 lanes).
    #pragma unroll
    for (int off = 32; off > 0; off >>= 1) {
        num += __shfl_xor(num, off);
        den += __shfl_xor(den, off);
    }
    if (lane == 0) {
        // num,den are 4x true sums; sentinels add 8 true -> +32 scaled.
        // 0.25*(4N)/(4D+32) == 0.25*N/(D+8). k1 zeroed out[n] this launch.
        atomicAdd(out + n, 0.25f * (num / (den + 32.0f)));
    }
}

extern "C" void kernel_launch(void* const* d_in, const int* in_sizes, int n_in,
                              void* d_out, int out_size, void* d_ws, size_t ws_size,
                              hipStream_t stream) {
    const int*   edge     = (const int*)  d_in[0];
    const int*   mid0     = (const int*)  d_in[1];
    const int*   mid1     = (const int*)  d_in[2];
    const float* pos      = (const float*)d_in[3];
    const float* field    = (const float*)d_in[4];
    const float* unc      = (const float*)d_in[5];
    const float* edge_mat = (const float*)d_in[6];
    float*       out      = (float*)d_out;
    unsigned long long* ws_mask = (unsigned long long*)d_ws; // 5.24 MB used

    mask_kernel<<<N_BATCH, 256, 0, stream>>>(edge, edge_mat, ws_mask, out);
    madgraph_kernel<<<N_BATCH, 256, 0, stream>>>(edge, mid0, mid1, pos,
                                                 field, unc, ws_mask, out);
}